// Round 7
// baseline (850.224 us; speedup 1.0000x reference)
//
#include <hip/hip_runtime.h>
#include <hip/hip_cooperative_groups.h>

namespace cg = cooperative_groups;

#define Bn 8
#define Hn 512
#define Wn 512
#define Cn 16
#define NBLK 1024
#define NTHR 256
#define NCOLB 128   // blocks doing column scans in phase A

typedef float fx4 __attribute__((ext_vector_type(4)));

__device__ __forceinline__ float dgf(float g) { return 2.0f / (1.0f + __expf(-g)); }

template<bool NT>
__device__ __forceinline__ void resample_two(const float* __restrict__ im,
                                             const float* __restrict__ grd,
                                             float* __restrict__ outp,
                                             long p0, int cg4)
{
    const long p1 = p0 + 64;
    float2 g0 = *(const float2*)&grd[p0 * 2];
    float2 g1 = *(const float2*)&grd[p1 * 2];

    int x0a = (int)floorf(g0.x), y0a = (int)floorf(g0.y);
    int x1a = min(max(x0a + 1, 0), Wn - 1), y1a = min(max(y0a + 1, 0), Hn - 1);
    x0a = min(max(x0a, 0), Wn - 1);  y0a = min(max(y0a, 0), Hn - 1);
    int x0b = (int)floorf(g1.x), y0b = (int)floorf(g1.y);
    int x1b = min(max(x0b + 1, 0), Wn - 1), y1b = min(max(y0b + 1, 0), Hn - 1);
    x0b = min(max(x0b, 0), Wn - 1);  y0b = min(max(y0b, 0), Hn - 1);

    const float* base0 = im + ((p0 >> 18) << 22) + cg4 * 4;
    const float* base1 = im + ((p1 >> 18) << 22) + cg4 * 4;

    fx4 A0 = *(const fx4*)(base0 + (((long)(y0a << 9) + x0a) << 4));
    fx4 B0 = *(const fx4*)(base0 + (((long)(y1a << 9) + x0a) << 4));
    fx4 C0 = *(const fx4*)(base0 + (((long)(y0a << 9) + x1a) << 4));
    fx4 D0 = *(const fx4*)(base0 + (((long)(y1a << 9) + x1a) << 4));
    fx4 A1 = *(const fx4*)(base1 + (((long)(y0b << 9) + x0b) << 4));
    fx4 B1 = *(const fx4*)(base1 + (((long)(y1b << 9) + x0b) << 4));
    fx4 C1 = *(const fx4*)(base1 + (((long)(y0b << 9) + x1b) << 4));
    fx4 D1 = *(const fx4*)(base1 + (((long)(y1b << 9) + x1b) << 4));

    // weights from CLIPPED coords (reference semantics: exact-edge -> zero weights)
    float wa0 = ((float)x1a - g0.x) * ((float)y1a - g0.y);
    float wb0 = ((float)x1a - g0.x) * (g0.y - (float)y0a);
    float wc0 = (g0.x - (float)x0a) * ((float)y1a - g0.y);
    float wd0 = (g0.x - (float)x0a) * (g0.y - (float)y0a);
    float wa1 = ((float)x1b - g1.x) * ((float)y1b - g1.y);
    float wb1 = ((float)x1b - g1.x) * (g1.y - (float)y0b);
    float wc1 = (g1.x - (float)x0b) * ((float)y1b - g1.y);
    float wd1 = (g1.x - (float)x0b) * (g1.y - (float)y0b);

    fx4 r0 = wa0 * A0 + wb0 * B0 + wc0 * C0 + wd0 * D0;
    fx4 r1 = wa1 * A1 + wb1 * B1 + wc1 * C1 + wd1 * D1;

    if (NT) {
        __builtin_nontemporal_store(r0, (fx4*)(outp + (p0 << 4) + cg4 * 4));
        __builtin_nontemporal_store(r1, (fx4*)(outp + (p1 << 4) + cg4 * 4));
    } else {
        *(fx4*)(outp + (p0 << 4) + cg4 * 4) = r0;
        *(fx4*)(outp + (p1 << 4) + cg4 * 4) = r1;
    }
}

__global__ __launch_bounds__(NTHR, 4) void fused_kernel(
    const float* __restrict__ mov,
    const float* __restrict__ defgrad,
    float* __restrict__ mov_def,
    float* __restrict__ ref_def,
    float* __restrict__ grid_norm,
    float* __restrict__ grid_inv)
{
    cg::grid_group grid = cg::this_grid();
    const int tid  = threadIdx.x;
    const int wave = tid >> 6;
    const int lane = tid & 63;
    const int b    = blockIdx.x;

    // ================= Phase A: warp-grid computation =================
    if (b < NCOLB) {
        // ---- column scans, y channel: block -> (batch b>>4, 32-col tile) ----
        __shared__ float partial[8][32];
        const int seg  = tid >> 5;            // 8 segments of 64 rows
        const int l32  = tid & 31;
        const int bb   = b >> 4;
        const int w    = ((b & 15) << 5) + l32;
        const long cbase = ((long)bb * Hn) * Wn + w;

        float e0 = dgf(defgrad[cbase * 2 + 1]);
        float sum = 0.f;
        #pragma unroll 8
        for (int i = 0; i < 64; ++i) {
            int h = (seg << 6) + i;
            sum += dgf(defgrad[(cbase + (long)h * Wn) * 2 + 1]);
        }
        partial[seg][l32] = sum;
        __syncthreads();
        float off = 0.f, tot = 0.f;
        #pragma unroll
        for (int j = 0; j < 8; ++j) {
            float p = partial[j][l32];
            if (j < seg) off += p;
            tot += p;
        }
        float denom = tot - e0;
        float run = off;
        #pragma unroll 4
        for (int i = 0; i < 64; ++i) {
            int h = (seg << 6) + i;
            long pidx = cbase + (long)h * Wn;
            run += dgf(defgrad[pidx * 2 + 1]);
            float norm = (h == Hn - 1) ? 511.0f : 511.0f * ((run - e0) / denom);
            grid_norm[pidx * 2 + 1] = norm;
            grid_inv[pidx * 2 + 1]  = 2.0f * (float)h - norm;
        }
    } else {
        // ---- row scans, x channel: thread t holds pixels w=2t, 2t+1 ----
        __shared__ float wsum[4];
        __shared__ float s0sh;
        for (int row = b - NCOLB; row < Bn * Hn; row += NBLK - NCOLB) {
            const long base = (long)row * Wn;
            fx4 gq = *(const fx4*)&defgrad[(base + 2 * tid) * 2]; // [x0,y0,x1,y1]
            float v0 = dgf(gq.x), v1 = dgf(gq.z);
            float s = v0 + v1;
            float x = s;
            #pragma unroll
            for (int o = 1; o < 64; o <<= 1) {
                float n = __shfl_up(x, o, 64);
                x += (lane >= o) ? n : 0.0f;
            }
            if (lane == 63) wsum[wave] = x;
            if (tid == 0)   s0sh = v0;
            __syncthreads();
            float pre = 0.f, tot = 0.f;
            #pragma unroll
            for (int j = 0; j < 4; ++j) {
                float p = wsum[j];
                if (j < wave) pre += p;
                tot += p;
            }
            float excl  = pre + x - s;          // exclusive prefix before w=2t
            float s0    = s0sh;
            float denom = tot - s0;
            float scan0 = excl + v0;
            float scan1 = excl + v0 + v1;
            int w0i = 2 * tid, w1i = 2 * tid + 1;
            float n0 = 511.0f * ((scan0 - s0) / denom);
            float n1 = (w1i == Wn - 1) ? 511.0f : 511.0f * ((scan1 - s0) / denom);
            grid_norm[(base + w0i) * 2] = n0;
            grid_inv [(base + w0i) * 2] = 2.0f * (float)w0i - n0;
            grid_norm[(base + w1i) * 2] = n1;
            grid_inv [(base + w1i) * 2] = 2.0f * (float)w1i - n1;
            __syncthreads();   // protect wsum/s0sh for next iteration
        }
    }

    // XCD-chunked logical block id: each XCD owns a contiguous 1/8 of pixels
    const int  lb  = ((b & 7) << 7) + (b >> 3);
    const long pixbase = (long)lb * 2048;
    const int  q   = tid >> 2;
    const int  cg4 = tid & 3;

    grid.sync();
    // ================= Phase B: mov_def = resample(mov, grid_norm) =================
    for (int it = 0; it < 16; ++it)
        resample_two<true>(mov, grid_norm, mov_def, pixbase + it * 128 + q, cg4);

    grid.sync();
    // ================= Phase C: ref_def = resample(mov_def, grid_inv) =================
    for (int it = 0; it < 16; ++it)
        resample_two<true>(mov_def, grid_inv, ref_def, pixbase + it * 128 + q, cg4);
}

extern "C" void kernel_launch(void* const* d_in, const int* in_sizes, int n_in,
                              void* d_out, int out_size, void* d_ws, size_t ws_size,
                              hipStream_t stream) {
    const float* mov     = (const float*)d_in[0];
    const float* defgrad = (const float*)d_in[2];
    float* out = (float*)d_out;

    const long N_img  = (long)Bn * Hn * Wn * Cn;   // 33554432
    const long N_grid = (long)Bn * Hn * Wn * 2;    // 4194304
    float* mov_def   = out;
    float* ref_def   = out + N_img;
    float* grid_norm = out + 2 * N_img;
    float* grid_inv  = out + 2 * N_img + N_grid;

    void* args[] = { (void*)&mov, (void*)&defgrad, (void*)&mov_def,
                     (void*)&ref_def, (void*)&grid_norm, (void*)&grid_inv };
    hipLaunchCooperativeKernel((const void*)fused_kernel,
                               dim3(NBLK), dim3(NTHR), args, 0, stream);
}